// Round 4
// baseline (410.101 us; speedup 1.0000x reference)
//
#include <hip/hip_runtime.h>
#include <math.h>

// B=4, H=16, S=2048, D=64 causal attention. Inputs fp32, OUTPUT fp32
// (reference dtype; harness compares in bf16-demoted space, 2% threshold).
// Flash-attention forward: 1 block = (head, 64-row Q tile), 4 waves x 16 Q rows.
// K/V tiles (64 rows) staged in LDS as bf16; mfma_f32_16x16x32_bf16 for QK^T and PV.
// No infinities anywhere; exp2 args clamped to >= -126.

#define S_LEN 2048
#define D_DIM 64
#define TQ 64
#define TK 64
#define LSTR 72    // LDS leading-dim stride in bf16 elems (144 B: 16B-aligned, 2-way banks only)
#define MNEG -30000.0f

typedef __attribute__((ext_vector_type(8))) short bf16x8;
typedef __attribute__((ext_vector_type(4))) float f32x4;

static __device__ __forceinline__ unsigned short f2bf(float f) {
    union { float f; unsigned int i; } c; c.f = f;
    return (unsigned short)((c.i + 0x7fffu + ((c.i >> 16) & 1u)) >> 16);
}

__global__ __launch_bounds__(256, 2)
void fa_fwd(const float* __restrict__ qg,
            const float* __restrict__ kg,
            const float* __restrict__ vg,
            float* __restrict__ og)
{
    const int head = blockIdx.y;
    const int q0   = blockIdx.x * TQ;
    const int tid  = threadIdx.x;
    const int wave = tid >> 6;
    const int lane = tid & 63;
    const int m16  = lane & 15;   // A-row / B-col / C-col index
    const int quad = lane >> 4;   // 0..3

    __shared__ unsigned short Kl[TK][LSTR];       // K tile bf16, row-major [kv][d]
    __shared__ unsigned short Vt[D_DIM][LSTR];    // V tile bf16, transposed [d][kv]
    __shared__ unsigned short Pl[4][16][LSTR];    // per-wave P tile [qrow][kv]

    const size_t hoff = (size_t)head * S_LEN * D_DIM;
    const float* qh = qg + hoff;
    const float* kh = kg + hoff;
    const float* vh = vg + hoff;

    // ---- Q fragments (A-layout: row=lane&15, k=quad*8+j), scaled by 1/8, fp32->bf16
    const int qrow_base = q0 + wave * 16;
    bf16x8 qf[2];
    {
        const float* qp = qh + (size_t)(qrow_base + m16) * D_DIM + quad * 8;
        #pragma unroll
        for (int c = 0; c < 2; ++c) {
            float4 a = *reinterpret_cast<const float4*>(qp + c * 32);
            float4 b = *reinterpret_cast<const float4*>(qp + c * 32 + 4);
            qf[c][0] = (short)f2bf(a.x * 0.125f);
            qf[c][1] = (short)f2bf(a.y * 0.125f);
            qf[c][2] = (short)f2bf(a.z * 0.125f);
            qf[c][3] = (short)f2bf(a.w * 0.125f);
            qf[c][4] = (short)f2bf(b.x * 0.125f);
            qf[c][5] = (short)f2bf(b.y * 0.125f);
            qf[c][6] = (short)f2bf(b.z * 0.125f);
            qf[c][7] = (short)f2bf(b.w * 0.125f);
        }
    }

    float m_i[4], l_i[4];
    f32x4 oacc[4];
    #pragma unroll
    for (int r = 0; r < 4; ++r) { m_i[r] = MNEG; l_i[r] = 0.f; }
    #pragma unroll
    for (int nc = 0; nc < 4; ++nc) oacc[nc] = (f32x4){0.f, 0.f, 0.f, 0.f};

    // K staging mapping: 1 thread = 16 elems of one row
    const int ksr = tid >> 2;              // 0..63 kv row
    const int ksc = (tid & 3) << 4;        // 0,16,32,48
    // V staging mapping (transpose): rotated ushort2 writes, full coverage
    const int va_ = lane >> 3;             // 0..7
    const int vb_ = lane & 7;              // 0..7
    const int vr0 = wave * 16 + 2 * vb_;   // even kv row
    const int vc0 = 8 * va_;               // d col group

    const float LOG2E = 1.4426950408889634f;

    for (int j0 = 0; j0 <= q0; j0 += TK) {
        __syncthreads();   // protect previous tile's LDS reads
        {
            // ---- stage K tile: fp32 -> bf16, row-major
            const float* kp = kh + (size_t)(j0 + ksr) * D_DIM + ksc;
            float4 k0 = reinterpret_cast<const float4*>(kp)[0];
            float4 k1 = reinterpret_cast<const float4*>(kp)[1];
            float4 k2 = reinterpret_cast<const float4*>(kp)[2];
            float4 k3 = reinterpret_cast<const float4*>(kp)[3];
            bf16x8 pk0, pk1;
            pk0[0] = (short)f2bf(k0.x); pk0[1] = (short)f2bf(k0.y);
            pk0[2] = (short)f2bf(k0.z); pk0[3] = (short)f2bf(k0.w);
            pk0[4] = (short)f2bf(k1.x); pk0[5] = (short)f2bf(k1.y);
            pk0[6] = (short)f2bf(k1.z); pk0[7] = (short)f2bf(k1.w);
            pk1[0] = (short)f2bf(k2.x); pk1[1] = (short)f2bf(k2.y);
            pk1[2] = (short)f2bf(k2.z); pk1[3] = (short)f2bf(k2.w);
            pk1[4] = (short)f2bf(k3.x); pk1[5] = (short)f2bf(k3.y);
            pk1[6] = (short)f2bf(k3.z); pk1[7] = (short)f2bf(k3.w);
            *reinterpret_cast<bf16x8*>(&Kl[ksr][ksc])     = pk0;
            *reinterpret_cast<bf16x8*>(&Kl[ksr][ksc + 8]) = pk1;

            // ---- stage V tile transposed: Vt[d][kv], fp32 -> bf16
            const float* vp = vh + (size_t)(j0 + vr0) * D_DIM + vc0;
            float4 v0a = reinterpret_cast<const float4*>(vp)[0];
            float4 v0b = reinterpret_cast<const float4*>(vp)[1];
            float4 v1a = reinterpret_cast<const float4*>(vp + D_DIM)[0];
            float4 v1b = reinterpret_cast<const float4*>(vp + D_DIM)[1];
            float r0[8] = {v0a.x, v0a.y, v0a.z, v0a.w, v0b.x, v0b.y, v0b.z, v0b.w};
            float r1[8] = {v1a.x, v1a.y, v1a.z, v1a.w, v1b.x, v1b.y, v1b.z, v1b.w};
            #pragma unroll
            for (int jj = 0; jj < 8; ++jj) {
                int j = (jj + va_) & 7;    // rotate write order -> 2-way banks max
                ushort2 pr;
                pr.x = f2bf(r0[j]);
                pr.y = f2bf(r1[j]);
                *reinterpret_cast<ushort2*>(&Vt[vc0 + j][vr0]) = pr;
            }
        }
        __syncthreads();

        // ---- S = Q K^T  (C-layout: row=quad*4+r -> q, col=nt*16+m16 -> kv)
        float sv[4][4];
        #pragma unroll
        for (int nt = 0; nt < 4; ++nt) {
            f32x4 acc = (f32x4){0.f, 0.f, 0.f, 0.f};
            bf16x8 kf0 = *reinterpret_cast<const bf16x8*>(&Kl[nt * 16 + m16][quad * 8]);
            bf16x8 kf1 = *reinterpret_cast<const bf16x8*>(&Kl[nt * 16 + m16][32 + quad * 8]);
            acc = __builtin_amdgcn_mfma_f32_16x16x32_bf16(qf[0], kf0, acc, 0, 0, 0);
            acc = __builtin_amdgcn_mfma_f32_16x16x32_bf16(qf[1], kf1, acc, 0, 0, 0);
            #pragma unroll
            for (int r = 0; r < 4; ++r) sv[nt][r] = acc[r];
        }

        // ---- causal mask: only the diagonal tile (j0 == q0) needs it
        if (j0 == q0) {
            #pragma unroll
            for (int nt = 0; nt < 4; ++nt)
                #pragma unroll
                for (int r = 0; r < 4; ++r)
                    if (nt * 16 + m16 > wave * 16 + quad * 4 + r) sv[nt][r] = MNEG;
        }

        // ---- online softmax (exp2 domain, all-finite, args clamped)
        float mnew[4], alpha[4], msc[4], rsum[4];
        #pragma unroll
        for (int r = 0; r < 4; ++r) {
            float rm = fmaxf(fmaxf(sv[0][r], sv[1][r]), fmaxf(sv[2][r], sv[3][r]));
            rm = fmaxf(rm, __shfl_xor(rm, 1, 64));
            rm = fmaxf(rm, __shfl_xor(rm, 2, 64));
            rm = fmaxf(rm, __shfl_xor(rm, 4, 64));
            rm = fmaxf(rm, __shfl_xor(rm, 8, 64));
            mnew[r]  = fmaxf(m_i[r], rm);
            alpha[r] = exp2f(fmaxf((m_i[r] - mnew[r]) * LOG2E, -126.f));
            msc[r]   = mnew[r] * LOG2E;
            m_i[r]   = mnew[r];
            rsum[r]  = 0.f;
        }

        // P = exp(S - m), write to per-wave LDS (bf16), accumulate row sums
        #pragma unroll
        for (int nt = 0; nt < 4; ++nt) {
            #pragma unroll
            for (int r = 0; r < 4; ++r) {
                float e = exp2f(fmaxf(fmaf(sv[nt][r], LOG2E, -msc[r]), -126.f));
                rsum[r] += e;
                Pl[wave][quad * 4 + r][nt * 16 + m16] = f2bf(e);
            }
        }
        #pragma unroll
        for (int r = 0; r < 4; ++r) {
            float rs = rsum[r];
            rs += __shfl_xor(rs, 1, 64);
            rs += __shfl_xor(rs, 2, 64);
            rs += __shfl_xor(rs, 4, 64);
            rs += __shfl_xor(rs, 8, 64);
            l_i[r] = alpha[r] * l_i[r] + rs;
        }

        // rescale O accumulator
        #pragma unroll
        for (int nc = 0; nc < 4; ++nc)
            #pragma unroll
            for (int r = 0; r < 4; ++r)
                oacc[nc][r] *= alpha[r];

        __syncthreads();   // P LDS writes visible before A-fragment read-back

        // ---- O += P V   (P via LDS round-trip: C-layout -> A-layout)
        bf16x8 pf0 = *reinterpret_cast<const bf16x8*>(&Pl[wave][m16][quad * 8]);
        bf16x8 pf1 = *reinterpret_cast<const bf16x8*>(&Pl[wave][m16][32 + quad * 8]);
        #pragma unroll
        for (int nc = 0; nc < 4; ++nc) {
            bf16x8 vf0 = *reinterpret_cast<const bf16x8*>(&Vt[nc * 16 + m16][quad * 8]);
            bf16x8 vf1 = *reinterpret_cast<const bf16x8*>(&Vt[nc * 16 + m16][32 + quad * 8]);
            oacc[nc] = __builtin_amdgcn_mfma_f32_16x16x32_bf16(pf0, vf0, oacc[nc], 0, 0, 0);
            oacc[nc] = __builtin_amdgcn_mfma_f32_16x16x32_bf16(pf1, vf1, oacc[nc], 0, 0, 0);
        }
    }

    // ---- epilogue: O / l, store fp32 (reference output dtype)
    float* oh = og + hoff;
    #pragma unroll
    for (int r = 0; r < 4; ++r) {
        float inv = 1.0f / l_i[r];
        size_t rb = (size_t)(qrow_base + quad * 4 + r) * D_DIM;
        #pragma unroll
        for (int nc = 0; nc < 4; ++nc)
            oh[rb + nc * 16 + m16] = oacc[nc][r] * inv;
    }
}

extern "C" void kernel_launch(void* const* d_in, const int* in_sizes, int n_in,
                              void* d_out, int out_size, void* d_ws, size_t ws_size,
                              hipStream_t stream) {
    const float* q = (const float*)d_in[0];
    const float* k = (const float*)d_in[1];
    const float* v = (const float*)d_in[2];
    float* o = (float*)d_out;
    dim3 grid(S_LEN / TQ, 64 /* B*H */);
    fa_fwd<<<grid, 256, 0, stream>>>(q, k, v, o);
}

// Round 5
// 237.425 us; speedup vs baseline: 1.7273x; 1.7273x over previous
//
#include <hip/hip_runtime.h>
#include <math.h>

// B=4, H=16, S=2048, D=64 causal attention. fp32 in, fp32 out.
// Flash-attention fwd, S^T formulation: S^T = K·Q^T (C cols = q) makes softmax
// per-lane (2 shuffles), P writes b64, alpha scalar. Tile pairing (i, 31-i)
// gives uniform 33 iters/block; 1024 blocks = 4/CU. Register prefetch of next
// K/V tile overlaps HBM with compute.

#define S_LEN 2048
#define D_DIM 64
#define TK 64
#define LSTR 72    // LDS row stride in shorts (144 B: 16B-aligned, 2-way banks only)
#define MNEG -30000.0f

typedef __attribute__((ext_vector_type(8))) short bf16x8;
typedef __attribute__((ext_vector_type(4))) float f32x4;

static __device__ __forceinline__ unsigned short f2bf(float f) {
    union { float ff; unsigned int i; } c; c.ff = f;
    return (unsigned short)((c.i + 0x8000u) >> 16);   // round-half-up, 2 VALU ops
}

__global__ __launch_bounds__(256, 4)
void fa_fwd(const float* __restrict__ qg,
            const float* __restrict__ kg,
            const float* __restrict__ vg,
            float* __restrict__ og)
{
    const int head = blockIdx.x;          // fast dim -> XCD spread, same-head L2 reuse
    const int pr   = blockIdx.y;          // 0..15, handles q-tiles {pr, 31-pr}
    const int tid  = threadIdx.x;
    const int wave = tid >> 6;
    const int lane = tid & 63;
    const int m16  = lane & 15;
    const int quad = lane >> 4;

    __shared__ unsigned short Kl[TK][LSTR];       // K tile bf16 [kv][d]
    __shared__ unsigned short Vt[D_DIM][LSTR];    // V tile bf16 transposed [d][kv]
    __shared__ unsigned short Pl[4][16][LSTR];    // per-wave P [q][kv]

    const size_t hoff = (size_t)head * S_LEN * D_DIM;
    const float* kh = kg + hoff;
    const float* vh = vg + hoff;

    const int ksr = tid >> 2;              // K stage: row
    const int ksc = (tid & 3) << 4;        // K stage: 16-float col chunk
    const int va  = lane >> 3;
    const int vb  = lane & 7;
    const int vrr = wave * 16 + 2 * vb;    // V stage: even kv row
    const int vcc = 8 * va;                // V stage: d group
    const float LOG2E = 1.4426950408889634f;

    for (int pass = 0; pass < 2; ++pass) {
        const int q0 = ((pass == 0) ? pr : (31 - pr)) * TK;

        // ---- Q fragment (B operand): B[k=d][n=q], n=m16, k=quad*8+j; scaled 1/8
        bf16x8 qf[2];
        {
            const float* qp = qg + hoff + (size_t)(q0 + wave * 16 + m16) * D_DIM + quad * 8;
            #pragma unroll
            for (int c = 0; c < 2; ++c) {
                float4 a = reinterpret_cast<const float4*>(qp + c * 32)[0];
                float4 b = reinterpret_cast<const float4*>(qp + c * 32)[1];
                qf[c][0] = (short)f2bf(a.x * 0.125f);
                qf[c][1] = (short)f2bf(a.y * 0.125f);
                qf[c][2] = (short)f2bf(a.z * 0.125f);
                qf[c][3] = (short)f2bf(a.w * 0.125f);
                qf[c][4] = (short)f2bf(b.x * 0.125f);
                qf[c][5] = (short)f2bf(b.y * 0.125f);
                qf[c][6] = (short)f2bf(b.z * 0.125f);
                qf[c][7] = (short)f2bf(b.w * 0.125f);
            }
        }

        float m_i = MNEG, l_i = 0.f;
        f32x4 oacc[4];
        #pragma unroll
        for (int nc = 0; nc < 4; ++nc) oacc[nc] = (f32x4){0.f, 0.f, 0.f, 0.f};

        // ---- prefetch tile 0 into registers
        float4 kA, kB, kC, kD, vA, vB, vC, vD;
        {
            const float* kp = kh + (size_t)ksr * D_DIM + ksc;
            kA = reinterpret_cast<const float4*>(kp)[0];
            kB = reinterpret_cast<const float4*>(kp)[1];
            kC = reinterpret_cast<const float4*>(kp)[2];
            kD = reinterpret_cast<const float4*>(kp)[3];
            const float* vp = vh + (size_t)vrr * D_DIM + vcc;
            vA = reinterpret_cast<const float4*>(vp)[0];
            vB = reinterpret_cast<const float4*>(vp)[1];
            vC = reinterpret_cast<const float4*>(vp + D_DIM)[0];
            vD = reinterpret_cast<const float4*>(vp + D_DIM)[1];
        }

        for (int j0 = 0; j0 <= q0; j0 += TK) {
            __syncthreads();   // all waves done reading previous tile's LDS
            {
                // ---- convert + store K tile (b128 writes)
                bf16x8 p0, p1;
                p0[0]=(short)f2bf(kA.x); p0[1]=(short)f2bf(kA.y); p0[2]=(short)f2bf(kA.z); p0[3]=(short)f2bf(kA.w);
                p0[4]=(short)f2bf(kB.x); p0[5]=(short)f2bf(kB.y); p0[6]=(short)f2bf(kB.z); p0[7]=(short)f2bf(kB.w);
                p1[0]=(short)f2bf(kC.x); p1[1]=(short)f2bf(kC.y); p1[2]=(short)f2bf(kC.z); p1[3]=(short)f2bf(kC.w);
                p1[4]=(short)f2bf(kD.x); p1[5]=(short)f2bf(kD.y); p1[6]=(short)f2bf(kD.z); p1[7]=(short)f2bf(kD.w);
                *reinterpret_cast<bf16x8*>(&Kl[ksr][ksc])     = p0;
                *reinterpret_cast<bf16x8*>(&Kl[ksr][ksc + 8]) = p1;

                // ---- convert + store V transposed (rotated writes: 2-way banks max)
                float r0[8] = {vA.x, vA.y, vA.z, vA.w, vB.x, vB.y, vB.z, vB.w};
                float r1[8] = {vC.x, vC.y, vC.z, vC.w, vD.x, vD.y, vD.z, vD.w};
                #pragma unroll
                for (int jj = 0; jj < 8; ++jj) {
                    int j = (jj + va) & 7;
                    ushort2 w;
                    w.x = f2bf(r0[j]);
                    w.y = f2bf(r1[j]);
                    *reinterpret_cast<ushort2*>(&Vt[vcc + j][vrr]) = w;
                }
            }
            __syncthreads();

            // ---- prefetch next K/V tile (in flight through the whole compute phase)
            if (j0 + TK <= q0) {
                const float* kp = kh + (size_t)(j0 + TK + ksr) * D_DIM + ksc;
                kA = reinterpret_cast<const float4*>(kp)[0];
                kB = reinterpret_cast<const float4*>(kp)[1];
                kC = reinterpret_cast<const float4*>(kp)[2];
                kD = reinterpret_cast<const float4*>(kp)[3];
                const float* vp = vh + (size_t)(j0 + TK + vrr) * D_DIM + vcc;
                vA = reinterpret_cast<const float4*>(vp)[0];
                vB = reinterpret_cast<const float4*>(vp)[1];
                vC = reinterpret_cast<const float4*>(vp + D_DIM)[0];
                vD = reinterpret_cast<const float4*>(vp + D_DIM)[1];
            }

            // ---- S^T = K·Q^T  (C: row=kv=nt*16+quad*4+r, col=q=m16)
            float sv[4][4];
            #pragma unroll
            for (int nt = 0; nt < 4; ++nt) {
                f32x4 acc = (f32x4){0.f, 0.f, 0.f, 0.f};
                bf16x8 kf0 = *reinterpret_cast<const bf16x8*>(&Kl[nt * 16 + m16][quad * 8]);
                bf16x8 kf1 = *reinterpret_cast<const bf16x8*>(&Kl[nt * 16 + m16][32 + quad * 8]);
                acc = __builtin_amdgcn_mfma_f32_16x16x32_bf16(kf0, qf[0], acc, 0, 0, 0);
                acc = __builtin_amdgcn_mfma_f32_16x16x32_bf16(kf1, qf[1], acc, 0, 0, 0);
                #pragma unroll
                for (int r = 0; r < 4; ++r) sv[nt][r] = acc[r];
            }

            // ---- causal mask (diagonal tile only): kv_local > q_local
            if (j0 == q0) {
                #pragma unroll
                for (int nt = 0; nt < 4; ++nt)
                    #pragma unroll
                    for (int r = 0; r < 4; ++r)
                        if (nt * 16 + quad * 4 + r > wave * 16 + m16) sv[nt][r] = MNEG;
            }

            // ---- online softmax: per-lane (q=m16), 2 shuffles per reduction
            float a0 = fmaxf(fmaxf(sv[0][0], sv[0][1]), fmaxf(sv[0][2], sv[0][3]));
            float a1 = fmaxf(fmaxf(sv[1][0], sv[1][1]), fmaxf(sv[1][2], sv[1][3]));
            float a2 = fmaxf(fmaxf(sv[2][0], sv[2][1]), fmaxf(sv[2][2], sv[2][3]));
            float a3 = fmaxf(fmaxf(sv[3][0], sv[3][1]), fmaxf(sv[3][2], sv[3][3]));
            float rm = fmaxf(fmaxf(a0, a1), fmaxf(a2, a3));
            rm = fmaxf(rm, __shfl_xor(rm, 16, 64));
            rm = fmaxf(rm, __shfl_xor(rm, 32, 64));
            float mnew  = fmaxf(m_i, rm);
            float alpha = exp2f(fmaxf((m_i - mnew) * LOG2E, -126.f));
            float msc   = mnew * LOG2E;
            m_i = mnew;

            float rs = 0.f;
            #pragma unroll
            for (int nt = 0; nt < 4; ++nt) {
                float e0 = exp2f(fmaxf(fmaf(sv[nt][0], LOG2E, -msc), -126.f));
                float e1 = exp2f(fmaxf(fmaf(sv[nt][1], LOG2E, -msc), -126.f));
                float e2 = exp2f(fmaxf(fmaf(sv[nt][2], LOG2E, -msc), -126.f));
                float e3 = exp2f(fmaxf(fmaf(sv[nt][3], LOG2E, -msc), -126.f));
                rs += (e0 + e1) + (e2 + e3);
                ushort4 w;
                w.x = f2bf(e0); w.y = f2bf(e1); w.z = f2bf(e2); w.w = f2bf(e3);
                *reinterpret_cast<ushort4*>(&Pl[wave][m16][nt * 16 + quad * 4]) = w;  // b64, 2-way
            }
            rs += __shfl_xor(rs, 16, 64);
            rs += __shfl_xor(rs, 32, 64);
            l_i = fmaf(alpha, l_i, rs);

            #pragma unroll
            for (int nc = 0; nc < 4; ++nc)
                #pragma unroll
                for (int r = 0; r < 4; ++r)
                    oacc[nc][r] *= alpha;

            // Pl is wave-private: intra-wave DS ordering only (keeps global
            // prefetch in flight — a __syncthreads here would drain vmcnt).
            asm volatile("s_waitcnt lgkmcnt(0)" ::: "memory");

            // ---- O^T += V^T·P^T  (A=V^T from Vt, B=P from Pl; C: row=d, col=q)
            bf16x8 pf0 = *reinterpret_cast<const bf16x8*>(&Pl[wave][m16][quad * 8]);
            bf16x8 pf1 = *reinterpret_cast<const bf16x8*>(&Pl[wave][m16][32 + quad * 8]);
            #pragma unroll
            for (int nc = 0; nc < 4; ++nc) {
                bf16x8 vf0 = *reinterpret_cast<const bf16x8*>(&Vt[nc * 16 + m16][quad * 8]);
                bf16x8 vf1 = *reinterpret_cast<const bf16x8*>(&Vt[nc * 16 + m16][32 + quad * 8]);
                oacc[nc] = __builtin_amdgcn_mfma_f32_16x16x32_bf16(vf0, pf0, oacc[nc], 0, 0, 0);
                oacc[nc] = __builtin_amdgcn_mfma_f32_16x16x32_bf16(vf1, pf1, oacc[nc], 0, 0, 0);
            }
        }

        // ---- epilogue: lane owns q=q0+wave*16+m16; O^T rows d=nc*16+quad*4+r -> float4
        float inv = 1.0f / l_i;
        float* op = og + hoff + (size_t)(q0 + wave * 16 + m16) * D_DIM;
        #pragma unroll
        for (int nc = 0; nc < 4; ++nc) {
            float4 o4;
            o4.x = oacc[nc][0] * inv;
            o4.y = oacc[nc][1] * inv;
            o4.z = oacc[nc][2] * inv;
            o4.w = oacc[nc][3] * inv;
            reinterpret_cast<float4*>(op + nc * 16 + quad * 4)[0] = o4;
        }
    }
}

extern "C" void kernel_launch(void* const* d_in, const int* in_sizes, int n_in,
                              void* d_out, int out_size, void* d_ws, size_t ws_size,
                              hipStream_t stream) {
    const float* q = (const float*)d_in[0];
    const float* k = (const float*)d_in[1];
    const float* v = (const float*)d_in[2];
    float* o = (float*)d_out;
    dim3 grid(64 /* B*H, fast -> XCD */, 16 /* tile pairs */);
    fa_fwd<<<grid, 256, 0, stream>>>(q, k, v, o);
}

// Round 6
// 224.514 us; speedup vs baseline: 1.8266x; 1.0575x over previous
//
#include <hip/hip_runtime.h>
#include <math.h>

// B=4, H=16, S=2048, D=64 causal attention. fp32 in, fp32 out.
// Flash-attention fwd, S^T formulation (C cols = q): per-lane softmax, 2 shuffles.
// Tile pairing (i, 31-i): uniform 33 iters/block, 1024 blocks = 4/CU.
// R6: raw v_exp_f32 (no OCML libcall, no clamps), uint-packed bf16 conversion.

#define S_LEN 2048
#define D_DIM 64
#define TK 64
#define LSTR 72    // LDS row stride in shorts (144 B: 16B-aligned)
#define MNEG -30000.0f

typedef __attribute__((ext_vector_type(8))) short bf16x8;
typedef __attribute__((ext_vector_type(4))) float f32x4;

static __device__ __forceinline__ float fast_exp2(float x) {
#if __has_builtin(__builtin_amdgcn_exp2f)
    return __builtin_amdgcn_exp2f(x);   // v_exp_f32: 2^x, large-negative -> 0
#else
    float r;
    asm volatile("v_exp_f32 %0, %1\n\ts_nop 1" : "=v"(r) : "v"(x));
    return r;
#endif
}

// round-half-up fp32->bf16 pair, packed into one dword (a=low, b=high)
static __device__ __forceinline__ unsigned int pack_bf16(float a, float b) {
    union { float f; unsigned int u; } ca, cb;
    ca.f = a; cb.f = b;
    unsigned int ua = ca.u + 0x8000u;
    unsigned int ub = cb.u + 0x8000u;
    return (ua >> 16) | (ub & 0xFFFF0000u);
}

__global__ __launch_bounds__(256, 4)
void fa_fwd(const float* __restrict__ qg,
            const float* __restrict__ kg,
            const float* __restrict__ vg,
            float* __restrict__ og)
{
    const int head = blockIdx.x;          // fast dim -> XCD spread
    const int pr   = blockIdx.y;          // 0..15: q-tiles {pr, 31-pr}
    const int tid  = threadIdx.x;
    const int wave = tid >> 6;
    const int lane = tid & 63;
    const int m16  = lane & 15;
    const int quad = lane >> 4;

    __shared__ unsigned short Kl[TK][LSTR];       // K tile bf16 [kv][d]
    __shared__ unsigned short Vt[D_DIM][LSTR];    // V tile bf16 transposed [d][kv]
    __shared__ unsigned short Pl[4][16][LSTR];    // per-wave P [q][kv]

    const size_t hoff = (size_t)head * S_LEN * D_DIM;
    const float* kh = kg + hoff;
    const float* vh = vg + hoff;

    const int ksr = tid >> 2;              // K stage: kv row
    const int ksc = (tid & 3) << 4;        // K stage: 16-elem col chunk
    const int va  = lane >> 3;
    const int vb  = lane & 7;
    const int vrr = wave * 16 + 2 * vb;    // V stage: even kv row
    const int vcc = 8 * va;                // V stage: d group
    const float LOG2E = 1.4426950408889634f;

    for (int pass = 0; pass < 2; ++pass) {
        const int q0 = ((pass == 0) ? pr : (31 - pr)) * TK;

        // ---- Q fragment (B operand): n=q=m16, k=d=quad*8+j; scaled 1/8
        bf16x8 qf[2];
        {
            const float* qp = qg + hoff + (size_t)(q0 + wave * 16 + m16) * D_DIM + quad * 8;
            #pragma unroll
            for (int c = 0; c < 2; ++c) {
                float4 a = reinterpret_cast<const float4*>(qp + c * 32)[0];
                float4 b = reinterpret_cast<const float4*>(qp + c * 32)[1];
                unsigned int u0 = pack_bf16(a.x * 0.125f, a.y * 0.125f);
                unsigned int u1 = pack_bf16(a.z * 0.125f, a.w * 0.125f);
                unsigned int u2 = pack_bf16(b.x * 0.125f, b.y * 0.125f);
                unsigned int u3 = pack_bf16(b.z * 0.125f, b.w * 0.125f);
                qf[c][0] = (short)(u0 & 0xFFFF); qf[c][1] = (short)(u0 >> 16);
                qf[c][2] = (short)(u1 & 0xFFFF); qf[c][3] = (short)(u1 >> 16);
                qf[c][4] = (short)(u2 & 0xFFFF); qf[c][5] = (short)(u2 >> 16);
                qf[c][6] = (short)(u3 & 0xFFFF); qf[c][7] = (short)(u3 >> 16);
            }
        }

        float m_i = MNEG, l_i = 0.f;
        f32x4 oacc[4];
        #pragma unroll
        for (int nc = 0; nc < 4; ++nc) oacc[nc] = (f32x4){0.f, 0.f, 0.f, 0.f};

        // ---- prefetch tile 0
        float4 kA, kB, kC, kD, vA, vB, vC, vD;
        {
            const float* kp = kh + (size_t)ksr * D_DIM + ksc;
            kA = reinterpret_cast<const float4*>(kp)[0];
            kB = reinterpret_cast<const float4*>(kp)[1];
            kC = reinterpret_cast<const float4*>(kp)[2];
            kD = reinterpret_cast<const float4*>(kp)[3];
            const float* vp = vh + (size_t)vrr * D_DIM + vcc;
            vA = reinterpret_cast<const float4*>(vp)[0];
            vB = reinterpret_cast<const float4*>(vp)[1];
            vC = reinterpret_cast<const float4*>(vp + D_DIM)[0];
            vD = reinterpret_cast<const float4*>(vp + D_DIM)[1];
        }

        for (int j0 = 0; j0 <= q0; j0 += TK) {
            __syncthreads();   // all waves done reading previous tile's LDS
            {
                // ---- K tile: pack + b128 stores
                uint4 w0, w1;
                w0.x = pack_bf16(kA.x, kA.y); w0.y = pack_bf16(kA.z, kA.w);
                w0.z = pack_bf16(kB.x, kB.y); w0.w = pack_bf16(kB.z, kB.w);
                w1.x = pack_bf16(kC.x, kC.y); w1.y = pack_bf16(kC.z, kC.w);
                w1.z = pack_bf16(kD.x, kD.y); w1.w = pack_bf16(kD.z, kD.w);
                *reinterpret_cast<uint4*>(&Kl[ksr][ksc])     = w0;
                *reinterpret_cast<uint4*>(&Kl[ksr][ksc + 8]) = w1;

                // ---- V tile transposed (rotated writes: spread banks)
                float r0[8] = {vA.x, vA.y, vA.z, vA.w, vB.x, vB.y, vB.z, vB.w};
                float r1[8] = {vC.x, vC.y, vC.z, vC.w, vD.x, vD.y, vD.z, vD.w};
                #pragma unroll
                for (int jj = 0; jj < 8; ++jj) {
                    int j = (jj + va) & 7;
                    *reinterpret_cast<unsigned int*>(&Vt[vcc + j][vrr]) = pack_bf16(r0[j], r1[j]);
                }
            }
            __syncthreads();

            // ---- prefetch next K/V tile
            if (j0 + TK <= q0) {
                const float* kp = kh + (size_t)(j0 + TK + ksr) * D_DIM + ksc;
                kA = reinterpret_cast<const float4*>(kp)[0];
                kB = reinterpret_cast<const float4*>(kp)[1];
                kC = reinterpret_cast<const float4*>(kp)[2];
                kD = reinterpret_cast<const float4*>(kp)[3];
                const float* vp = vh + (size_t)(j0 + TK + vrr) * D_DIM + vcc;
                vA = reinterpret_cast<const float4*>(vp)[0];
                vB = reinterpret_cast<const float4*>(vp)[1];
                vC = reinterpret_cast<const float4*>(vp + D_DIM)[0];
                vD = reinterpret_cast<const float4*>(vp + D_DIM)[1];
            }

            // ---- S^T = K·Q^T  (C: row=kv=nt*16+quad*4+r, col=q=m16)
            float sv[4][4];
            #pragma unroll
            for (int nt = 0; nt < 4; ++nt) {
                f32x4 acc = (f32x4){0.f, 0.f, 0.f, 0.f};
                bf16x8 kf0 = *reinterpret_cast<const bf16x8*>(&Kl[nt * 16 + m16][quad * 8]);
                bf16x8 kf1 = *reinterpret_cast<const bf16x8*>(&Kl[nt * 16 + m16][32 + quad * 8]);
                acc = __builtin_amdgcn_mfma_f32_16x16x32_bf16(kf0, qf[0], acc, 0, 0, 0);
                acc = __builtin_amdgcn_mfma_f32_16x16x32_bf16(kf1, qf[1], acc, 0, 0, 0);
                #pragma unroll
                for (int r = 0; r < 4; ++r) sv[nt][r] = acc[r];
            }

            // ---- causal mask (diagonal tile only)
            if (j0 == q0) {
                #pragma unroll
                for (int nt = 0; nt < 4; ++nt)
                    #pragma unroll
                    for (int r = 0; r < 4; ++r)
                        if (nt * 16 + quad * 4 + r > wave * 16 + m16) sv[nt][r] = MNEG;
            }

            // ---- online softmax: per-lane, 2 shuffles per reduction
            float a0 = fmaxf(fmaxf(sv[0][0], sv[0][1]), fmaxf(sv[0][2], sv[0][3]));
            float a1 = fmaxf(fmaxf(sv[1][0], sv[1][1]), fmaxf(sv[1][2], sv[1][3]));
            float a2 = fmaxf(fmaxf(sv[2][0], sv[2][1]), fmaxf(sv[2][2], sv[2][3]));
            float a3 = fmaxf(fmaxf(sv[3][0], sv[3][1]), fmaxf(sv[3][2], sv[3][3]));
            float rm = fmaxf(fmaxf(a0, a1), fmaxf(a2, a3));
            rm = fmaxf(rm, __shfl_xor(rm, 16, 64));
            rm = fmaxf(rm, __shfl_xor(rm, 32, 64));
            float mnew  = fmaxf(m_i, rm);
            float alpha = fast_exp2((m_i - mnew) * LOG2E);   // -> 0 on first iter
            float msc   = mnew * LOG2E;
            m_i = mnew;

            float rs = 0.f;
            #pragma unroll
            for (int nt = 0; nt < 4; ++nt) {
                float e0 = fast_exp2(fmaf(sv[nt][0], LOG2E, -msc));
                float e1 = fast_exp2(fmaf(sv[nt][1], LOG2E, -msc));
                float e2 = fast_exp2(fmaf(sv[nt][2], LOG2E, -msc));
                float e3 = fast_exp2(fmaf(sv[nt][3], LOG2E, -msc));
                rs += (e0 + e1) + (e2 + e3);
                uint2 pw;
                pw.x = pack_bf16(e0, e1);
                pw.y = pack_bf16(e2, e3);
                *reinterpret_cast<uint2*>(&Pl[wave][m16][nt * 16 + quad * 4]) = pw;
            }
            rs += __shfl_xor(rs, 16, 64);
            rs += __shfl_xor(rs, 32, 64);
            l_i = fmaf(alpha, l_i, rs);

            #pragma unroll
            for (int nc = 0; nc < 4; ++nc)
                #pragma unroll
                for (int r = 0; r < 4; ++r)
                    oacc[nc][r] *= alpha;

            // Pl is wave-private: intra-wave DS ordering only (keeps global
            // prefetch in flight — __syncthreads here would drain vmcnt).
            asm volatile("s_waitcnt lgkmcnt(0)" ::: "memory");

            // ---- O^T += V^T·P^T  (C: row=d, col=q)
            bf16x8 pf0 = *reinterpret_cast<const bf16x8*>(&Pl[wave][m16][quad * 8]);
            bf16x8 pf1 = *reinterpret_cast<const bf16x8*>(&Pl[wave][m16][32 + quad * 8]);
            #pragma unroll
            for (int nc = 0; nc < 4; ++nc) {
                bf16x8 vf0 = *reinterpret_cast<const bf16x8*>(&Vt[nc * 16 + m16][quad * 8]);
                bf16x8 vf1 = *reinterpret_cast<const bf16x8*>(&Vt[nc * 16 + m16][32 + quad * 8]);
                oacc[nc] = __builtin_amdgcn_mfma_f32_16x16x32_bf16(vf0, pf0, oacc[nc], 0, 0, 0);
                oacc[nc] = __builtin_amdgcn_mfma_f32_16x16x32_bf16(vf1, pf1, oacc[nc], 0, 0, 0);
            }
        }

        // ---- epilogue: lane owns q=q0+wave*16+m16; O^T rows d -> float4 stores
        float inv = 1.0f / l_i;
        float* op = og + hoff + (size_t)(q0 + wave * 16 + m16) * D_DIM;
        #pragma unroll
        for (int nc = 0; nc < 4; ++nc) {
            float4 o4;
            o4.x = oacc[nc][0] * inv;
            o4.y = oacc[nc][1] * inv;
            o4.z = oacc[nc][2] * inv;
            o4.w = oacc[nc][3] * inv;
            reinterpret_cast<float4*>(op + nc * 16 + quad * 4)[0] = o4;
        }
    }
}

extern "C" void kernel_launch(void* const* d_in, const int* in_sizes, int n_in,
                              void* d_out, int out_size, void* d_ws, size_t ws_size,
                              hipStream_t stream) {
    const float* q = (const float*)d_in[0];
    const float* k = (const float*)d_in[1];
    const float* v = (const float*)d_in[2];
    float* o = (float*)d_out;
    dim3 grid(64 /* B*H */, 16 /* tile pairs */);
    fa_fwd<<<grid, 256, 0, stream>>>(q, k, v, o);
}